// Round 3
// baseline (1157.825 us; speedup 1.0000x reference)
//
#include <hip/hip_runtime.h>
#include <hip/hip_bf16.h>
#include <math.h>

#define F_IN 512
#define HID  16
#define C_OUT 40

#define BSH    7            // 128 nodes per bucket
#define BNODES 128
#define MAXNB  1024         // N=100000 -> NB=782
#define APAD   17           // LDS acc row stride (floats) — breaks bank aliasing

#define EPB 8192            // edges per block in count/partition
#define CTH 512             // threads in count/partition

// ---------------------------------------------------------------------------
// K0: zero global bucket counters
// ---------------------------------------------------------------------------
__global__ __launch_bounds__(1024) void k_zero(int* __restrict__ g, int n) {
    int t = threadIdx.x;
    if (t < n) g[t] = 0;
}

// ---------------------------------------------------------------------------
// K1: bucket histogram via LDS (305K global atomics instead of 3.2M)
// ---------------------------------------------------------------------------
__global__ __launch_bounds__(CTH) void k_count(const int* __restrict__ col,
                                               int* __restrict__ gcnt,
                                               int E, int NB) {
    __shared__ int lc[MAXNB];
    int t = threadIdx.x;
    for (int i = t; i < NB; i += CTH) lc[i] = 0;
    __syncthreads();
    int base = blockIdx.x * EPB;
#pragma unroll
    for (int i = 0; i < EPB / CTH; ++i) {
        int e = base + t + i * CTH;
        if (e < E) atomicAdd(&lc[col[e] >> BSH], 1);
    }
    __syncthreads();
    for (int i = t; i < NB; i += CTH)
        if (lc[i]) atomicAdd(&gcnt[i], lc[i]);
}

// ---------------------------------------------------------------------------
// K2: exclusive scan of bucket counts (NB <= 1024, single block)
// ---------------------------------------------------------------------------
__global__ __launch_bounds__(1024) void k_scan(const int* __restrict__ gcnt,
                                               int* __restrict__ bo,
                                               int* __restrict__ bcur,
                                               int NB, int E) {
    __shared__ int s[1024];
    int t = threadIdx.x;
    int v = (t < NB) ? gcnt[t] : 0;
    s[t] = v;
    __syncthreads();
    for (int off = 1; off < 1024; off <<= 1) {
        int x = (t >= off) ? s[t - off] : 0;
        __syncthreads();
        s[t] += x;
        __syncthreads();
    }
    if (t < NB) { int o = s[t] - v; bo[t] = o; bcur[t] = o; }
    if (t == 0) bo[NB] = E;
}

// ---------------------------------------------------------------------------
// K3: partition edges into buckets, contiguous run per (block,bucket)
// record: .x = (row<<7) | col_low, .y = ew bits
// ---------------------------------------------------------------------------
__global__ __launch_bounds__(CTH) void k_part(const int* __restrict__ row,
                                              const int* __restrict__ col,
                                              const float* __restrict__ ew,
                                              int* __restrict__ bcur,
                                              int2* __restrict__ st,
                                              int E, int NB) {
    __shared__ int lc[MAXNB];
    __shared__ int lb[MAXNB];
    int t = threadIdx.x;
    for (int i = t; i < NB; i += CTH) lc[i] = 0;
    __syncthreads();
    int base = blockIdx.x * EPB;
#pragma unroll
    for (int i = 0; i < EPB / CTH; ++i) {
        int e = base + t + i * CTH;
        if (e < E) atomicAdd(&lc[col[e] >> BSH], 1);
    }
    __syncthreads();
    for (int i = t; i < NB; i += CTH) {
        int c = lc[i];
        lb[i] = c ? atomicAdd(&bcur[i], c) : 0;
    }
    __syncthreads();
    for (int i = t; i < NB; i += CTH) lc[i] = 0;  // reuse as rank counter
    __syncthreads();
#pragma unroll
    for (int i = 0; i < EPB / CTH; ++i) {
        int e = base + t + i * CTH;
        if (e < E) {
            int c = col[e];
            int b = c >> BSH;
            int r = atomicAdd(&lc[b], 1);
            st[lb[b] + r] = make_int2((row[e] << BSH) | (c & (BNODES - 1)),
                                      __float_as_int(ew[e]));
        }
    }
}

// ---------------------------------------------------------------------------
// K4: dinv = rsqrt(1 + sum ew) per node, bucket-local LDS accumulation
// ---------------------------------------------------------------------------
__global__ __launch_bounds__(256) void k_degsum(const int* __restrict__ bo,
                                                const int2* __restrict__ st,
                                                float* __restrict__ dinv, int N) {
    __shared__ float deg[BNODES];
    int t = threadIdx.x;
    int b = blockIdx.x;
    if (t < BNODES) deg[t] = 0.0f;
    __syncthreads();
    int beg = bo[b], end = bo[b + 1];
    for (int e = beg + t; e < end; e += 256) {
        int2 rec = st[e];
        atomicAdd(&deg[rec.x & (BNODES - 1)], __int_as_float(rec.y));
    }
    __syncthreads();
    if (t < BNODES) {
        int n = b * BNODES + t;
        if (n < N) dinv[n] = rsqrtf(1.0f + deg[t]);
    }
}

// ---------------------------------------------------------------------------
// K5: h1' = dinv * (x @ W1)  — thread per node, W wave-uniform (scalar loads)
// ---------------------------------------------------------------------------
__global__ __launch_bounds__(256) void k_gemm1(const float* __restrict__ x,
                                               const float* __restrict__ W,
                                               const float* __restrict__ dinv,
                                               float* __restrict__ h, int N) {
    int n = blockIdx.x * 256 + threadIdx.x;
    if (n >= N) return;
    float acc[HID];
#pragma unroll
    for (int j = 0; j < HID; ++j) acc[j] = 0.0f;
    const float4* xr = (const float4*)(x + (size_t)n * F_IN);
#pragma unroll 4
    for (int k4 = 0; k4 < F_IN / 4; ++k4) {
        float4 xv = xr[k4];
        const float* wk = W + k4 * 4 * HID;   // wave-uniform
#pragma unroll
        for (int j = 0; j < HID; ++j) acc[j] += xv.x * wk[j];
#pragma unroll
        for (int j = 0; j < HID; ++j) acc[j] += xv.y * wk[HID + j];
#pragma unroll
        for (int j = 0; j < HID; ++j) acc[j] += xv.z * wk[2 * HID + j];
#pragma unroll
        for (int j = 0; j < HID; ++j) acc[j] += xv.w * wk[3 * HID + j];
    }
    float d = dinv[n];
    float4* hp = (float4*)(h + (size_t)n * HID);
    hp[0] = make_float4(d * acc[0], d * acc[1], d * acc[2], d * acc[3]);
    hp[1] = make_float4(d * acc[4], d * acc[5], d * acc[6], d * acc[7]);
    hp[2] = make_float4(d * acc[8], d * acc[9], d * acc[10], d * acc[11]);
    hp[3] = make_float4(d * acc[12], d * acc[13], d * acc[14], d * acc[15]);
}

// ---------------------------------------------------------------------------
// K6: aggregate per bucket with LDS atomics.
// src is dinv-pre-scaled. out[c] = dinv[c]*(sum ew*src[r] + src[c]) [+b, relu, *dinv]
// L1=true:  dst = dinv * relu(out + b1)   (produces a1' for next layer)
// L1=false: dst = out                     (produces g for epilogue)
// ---------------------------------------------------------------------------
template <bool L1>
__global__ __launch_bounds__(256) void k_agg(const int* __restrict__ bo,
                                             const int2* __restrict__ st,
                                             const float* __restrict__ dinv,
                                             const float* __restrict__ src,
                                             const float* __restrict__ bias,
                                             float* __restrict__ dst, int N) {
    __shared__ float acc[BNODES * APAD];
    int t = threadIdx.x;
    int b = blockIdx.x;
    for (int i = t; i < BNODES * APAD; i += 256) acc[i] = 0.0f;
    __syncthreads();
    int beg = bo[b], end = bo[b + 1];
    int q = t & 3, slot = t >> 2;
    for (int e = beg + slot; e < end; e += 64) {
        int2 rec = st[e];
        int cl = rec.x & (BNODES - 1);
        int r  = rec.x >> BSH;
        float w = __int_as_float(rec.y);
        float4 v = ((const float4*)(src + (size_t)r * HID))[q];
        float* a = acc + cl * APAD + q * 4;
        atomicAdd(a + 0, w * v.x);
        atomicAdd(a + 1, w * v.y);
        atomicAdd(a + 2, w * v.z);
        atomicAdd(a + 3, w * v.w);
    }
    __syncthreads();
    for (int i = t; i < BNODES * HID; i += 256) {
        int cl = i >> 4, j = i & 15;
        int n = b * BNODES + cl;
        if (n < N) {
            float d = dinv[n];
            float s = src[(size_t)n * HID + j];
            float v = d * (acc[cl * APAD + j] + s);
            if (L1) v = d * fmaxf(v + bias[j], 0.0f);
            dst[(size_t)n * HID + j] = v;
        }
    }
}

// ---------------------------------------------------------------------------
// K7: epilogue — logits = g@W2 + b2; log_softmax. One wave per node.
// ---------------------------------------------------------------------------
__global__ __launch_bounds__(256) void k_epilogue(const float* __restrict__ g,
                                                  const float* __restrict__ W2,
                                                  const float* __restrict__ b2,
                                                  float* __restrict__ out, int N) {
    __shared__ float Ws[HID * C_OUT];
    __shared__ float bs[C_OUT];
    int tid = threadIdx.x;
    for (int i = tid; i < HID * C_OUT; i += 256) Ws[i] = W2[i];
    if (tid < C_OUT) bs[tid] = b2[tid];
    __syncthreads();

    int lane = tid & 63;
    int w = tid >> 6;
    int n = blockIdx.x * 4 + w;
    if (n >= N) return;

    float logit = -INFINITY;
    if (lane < C_OUT) {
        float acc = bs[lane];
        const float* gr = g + (size_t)n * HID;
#pragma unroll
        for (int j = 0; j < HID; ++j) acc += gr[j] * Ws[j * C_OUT + lane];
        logit = acc;
    }
    float m = logit;
#pragma unroll
    for (int off = 32; off > 0; off >>= 1) m = fmaxf(m, __shfl_xor(m, off, 64));
    float ex = (lane < C_OUT) ? __expf(logit - m) : 0.0f;
    float s = ex;
#pragma unroll
    for (int off = 32; off > 0; off >>= 1) s += __shfl_xor(s, off, 64);
    if (lane < C_OUT) out[(size_t)n * C_OUT + lane] = logit - m - __logf(s);
}

// ---------------------------------------------------------------------------
extern "C" void kernel_launch(void* const* d_in, const int* in_sizes, int n_in,
                              void* d_out, int out_size, void* d_ws, size_t ws_size,
                              hipStream_t stream) {
    const float* x   = (const float*)d_in[0];
    const int*   ei  = (const int*)d_in[1];
    const float* ew  = (const float*)d_in[2];
    const float* W1  = (const float*)d_in[3];
    const float* b1  = (const float*)d_in[4];
    const float* W2  = (const float*)d_in[5];
    const float* b2  = (const float*)d_in[6];
    float* out = (float*)d_out;

    const int N = in_sizes[0] / F_IN;          // 100000
    const int E = in_sizes[2];                 // 3200000
    const int* row = ei;
    const int* col = ei + E;
    const int NB = (N + BNODES - 1) >> BSH;    // 782

    // workspace carve (4-byte words)
    int* wsi = (int*)d_ws;
    size_t o = 0;
    int* gcnt  = wsi + o; o += MAXNB;
    int* bo    = wsi + o; o += MAXNB + 1;
    int* bcur  = wsi + o; o += MAXNB;
    float* dinv = (float*)(wsi + o); o += N;
    float* h1   = (float*)(wsi + o); o += (size_t)N * HID;   // dinv-scaled
    float* a1   = (float*)(wsi + o); o += (size_t)N * HID;   // dinv-scaled
    float* g    = (float*)(wsi + o); o += (size_t)N * HID;
    int2* st    = (int2*)(wsi + o); o += (size_t)E * 2;

    int gC = (E + EPB - 1) / EPB;              // 391

    k_zero<<<1, 1024, 0, stream>>>(gcnt, NB);
    k_count<<<gC, CTH, 0, stream>>>(col, gcnt, E, NB);
    k_scan<<<1, 1024, 0, stream>>>(gcnt, bo, bcur, NB, E);
    k_part<<<gC, CTH, 0, stream>>>(row, col, ew, bcur, st, E, NB);
    k_degsum<<<NB, 256, 0, stream>>>(bo, st, dinv, N);
    k_gemm1<<<(N + 255) / 256, 256, 0, stream>>>(x, W1, dinv, h1, N);
    k_agg<true><<<NB, 256, 0, stream>>>(bo, st, dinv, h1, b1, a1, N);
    k_agg<false><<<NB, 256, 0, stream>>>(bo, st, dinv, a1, nullptr, g, N);
    k_epilogue<<<(N + 3) / 4, 256, 0, stream>>>(g, W2, b2, out, N);
}

// Round 4
// 631.493 us; speedup vs baseline: 1.8335x; 1.8335x over previous
//
#include <hip/hip_runtime.h>
#include <hip/hip_bf16.h>
#include <math.h>

#define F_IN 512
#define HID  16
#define C_OUT 40

#define BSH    7            // 128 nodes per coarse bucket
#define BNODES 128
#define MAXNB  1024         // N=100000 -> NB=782

#define EPB 8192            // edges per block in count/partition
#define CTH 512

__device__ __forceinline__ unsigned short f2bf(float f) {
    unsigned u = __float_as_uint(f);
    unsigned r = (u + 0x7FFF + ((u >> 16) & 1)) >> 16;   // RNE
    return (unsigned short)r;
}
__device__ __forceinline__ float bf2f(unsigned short h) {
    return __uint_as_float(((unsigned)h) << 16);
}

// ---------------------------------------------------------------------------
// K0: zero global bucket counters
// ---------------------------------------------------------------------------
__global__ __launch_bounds__(1024) void k_zero(int* __restrict__ g, int n) {
    int t = threadIdx.x;
    if (t < n) g[t] = 0;
}

// ---------------------------------------------------------------------------
// K1: coarse bucket histogram via LDS
// ---------------------------------------------------------------------------
__global__ __launch_bounds__(CTH) void k_count(const int* __restrict__ col,
                                               int* __restrict__ gcnt,
                                               int E, int NB) {
    __shared__ int lc[MAXNB];
    int t = threadIdx.x;
    for (int i = t; i < NB; i += CTH) lc[i] = 0;
    __syncthreads();
    int base = blockIdx.x * EPB;
#pragma unroll
    for (int i = 0; i < EPB / CTH; ++i) {
        int e = base + t + i * CTH;
        if (e < E) atomicAdd(&lc[col[e] >> BSH], 1);
    }
    __syncthreads();
    for (int i = t; i < NB; i += CTH)
        if (lc[i]) atomicAdd(&gcnt[i], lc[i]);
}

// ---------------------------------------------------------------------------
// K2: exclusive scan of bucket counts; also offs[N] = E sentinel
// ---------------------------------------------------------------------------
__global__ __launch_bounds__(1024) void k_scan(const int* __restrict__ gcnt,
                                               int* __restrict__ bo,
                                               int* __restrict__ bcur,
                                               int* __restrict__ offs,
                                               int NB, int N, int E) {
    __shared__ int s[1024];
    int t = threadIdx.x;
    int v = (t < NB) ? gcnt[t] : 0;
    s[t] = v;
    __syncthreads();
    for (int off = 1; off < 1024; off <<= 1) {
        int x = (t >= off) ? s[t - off] : 0;
        __syncthreads();
        s[t] += x;
        __syncthreads();
    }
    if (t < NB) { int o = s[t] - v; bo[t] = o; bcur[t] = o; }
    if (t == 0) { bo[NB] = E; offs[N] = E; }
}

// ---------------------------------------------------------------------------
// K3: partition edges into coarse buckets. record .x=(row<<7)|col_low, .y=ew
// ---------------------------------------------------------------------------
__global__ __launch_bounds__(CTH) void k_part(const int* __restrict__ row,
                                              const int* __restrict__ col,
                                              const float* __restrict__ ew,
                                              int* __restrict__ bcur,
                                              int2* __restrict__ st,
                                              int E, int NB) {
    __shared__ int lc[MAXNB];
    __shared__ int lb[MAXNB];
    int t = threadIdx.x;
    for (int i = t; i < NB; i += CTH) lc[i] = 0;
    __syncthreads();
    int base = blockIdx.x * EPB;
#pragma unroll
    for (int i = 0; i < EPB / CTH; ++i) {
        int e = base + t + i * CTH;
        if (e < E) atomicAdd(&lc[col[e] >> BSH], 1);
    }
    __syncthreads();
    for (int i = t; i < NB; i += CTH) {
        int c = lc[i];
        lb[i] = c ? atomicAdd(&bcur[i], c) : 0;
    }
    __syncthreads();
    for (int i = t; i < NB; i += CTH) lc[i] = 0;  // reuse as rank counter
    __syncthreads();
#pragma unroll
    for (int i = 0; i < EPB / CTH; ++i) {
        int e = base + t + i * CTH;
        if (e < E) {
            int c = col[e];
            int b = c >> BSH;
            int r = atomicAdd(&lc[b], 1);
            st[lb[b] + r] = make_int2((row[e] << BSH) | (c & (BNODES - 1)),
                                      __float_as_int(ew[e]));
        }
    }
}

// ---------------------------------------------------------------------------
// K4: per-bucket exact counting sort (two passes, no record buffer in LDS).
// Produces st2 sorted by destination node (.x=row, .y=ew), per-node offs,
// and dinv = rsqrt(1 + sum ew) as a free by-product.
// ---------------------------------------------------------------------------
__global__ __launch_bounds__(256) void k_sort(const int* __restrict__ bo,
                                              const int2* __restrict__ st,
                                              int2* __restrict__ st2,
                                              int* __restrict__ offs,
                                              float* __restrict__ dinv, int N) {
    __shared__ int cnt[BNODES];
    __shared__ float wsum[BNODES];
    __shared__ int off[BNODES];
    int t = threadIdx.x;
    int b = blockIdx.x;
    if (t < BNODES) { cnt[t] = 0; wsum[t] = 0.0f; }
    __syncthreads();
    int beg = bo[b], end = bo[b + 1];
    // pass A: histogram + weighted degree
    for (int e = beg + t; e < end; e += 256) {
        int2 rec = st[e];
        int cl = rec.x & (BNODES - 1);
        atomicAdd(&cnt[cl], 1);
        atomicAdd(&wsum[cl], __int_as_float(rec.y));
    }
    __syncthreads();
    // scan cnt[128] (Hillis-Steele)
    if (t < BNODES) off[t] = cnt[t];
    __syncthreads();
    for (int o = 1; o < BNODES; o <<= 1) {
        int v = (t < BNODES && t >= o) ? off[t - o] : 0;
        __syncthreads();
        if (t < BNODES) off[t] += v;
        __syncthreads();
    }
    if (t < BNODES) {
        int ex = off[t] - cnt[t];       // exclusive
        off[t] = ex;
        int n = b * BNODES + t;
        if (n < N) {
            offs[n] = beg + ex;
            dinv[n] = rsqrtf(1.0f + wsum[t]);
        }
        cnt[t] = 0;                     // reuse as rank counter
    }
    __syncthreads();
    // pass B: place
    for (int e = beg + t; e < end; e += 256) {
        int2 rec = st[e];
        int cl = rec.x & (BNODES - 1);
        int r = atomicAdd(&cnt[cl], 1);
        st2[beg + off[cl] + r] = make_int2(rec.x >> BSH, rec.y);
    }
}

// ---------------------------------------------------------------------------
// K5: h1' = dinv * (x @ W1), stored bf16 (16 x bf16 = 32 B per node)
// ---------------------------------------------------------------------------
__global__ __launch_bounds__(256) void k_gemm1(const float* __restrict__ x,
                                               const float* __restrict__ W,
                                               const float* __restrict__ dinv,
                                               unsigned short* __restrict__ hb,
                                               int N) {
    int n = blockIdx.x * 256 + threadIdx.x;
    if (n >= N) return;
    float acc[HID];
#pragma unroll
    for (int j = 0; j < HID; ++j) acc[j] = 0.0f;
    const float4* xr = (const float4*)(x + (size_t)n * F_IN);
#pragma unroll 4
    for (int k4 = 0; k4 < F_IN / 4; ++k4) {
        float4 xv = xr[k4];
        const float* wk = W + k4 * 4 * HID;   // wave-uniform -> scalar loads
#pragma unroll
        for (int j = 0; j < HID; ++j) acc[j] += xv.x * wk[j];
#pragma unroll
        for (int j = 0; j < HID; ++j) acc[j] += xv.y * wk[HID + j];
#pragma unroll
        for (int j = 0; j < HID; ++j) acc[j] += xv.z * wk[2 * HID + j];
#pragma unroll
        for (int j = 0; j < HID; ++j) acc[j] += xv.w * wk[3 * HID + j];
    }
    float d = dinv[n];
    unsigned pk[8];
#pragma unroll
    for (int j = 0; j < 8; ++j)
        pk[j] = (unsigned)f2bf(d * acc[2 * j]) |
                ((unsigned)f2bf(d * acc[2 * j + 1]) << 16);
    uint4* hp = (uint4*)(hb + (size_t)n * HID);
    hp[0] = make_uint4(pk[0], pk[1], pk[2], pk[3]);
    hp[1] = make_uint4(pk[4], pk[5], pk[6], pk[7]);
}

// ---------------------------------------------------------------------------
// K6: layer-1 aggregate. Wave per node; lane = 4*i+q (i edge slot, q dim quad).
// a1'[n] = dinv * relu(dinv*(sum ew*h1'[r] + h1'[n]) + b1), stored bf16.
// ---------------------------------------------------------------------------
__global__ __launch_bounds__(256) void k_agg1(const int* __restrict__ offs,
                                              const int2* __restrict__ st2,
                                              const float* __restrict__ dinv,
                                              const unsigned short* __restrict__ srcb,
                                              const float* __restrict__ bias,
                                              unsigned short* __restrict__ dstb,
                                              int N) {
    int t = threadIdx.x;
    int lane = t & 63, w = t >> 6;
    int n = blockIdx.x * 4 + w;
    if (n >= N) return;
    int q = lane & 3, i = lane >> 2;
    int beg = offs[n], end = offs[n + 1];
    float4 acc = make_float4(0.f, 0.f, 0.f, 0.f);
    for (int e = beg + i; e < end; e += 16) {
        int2 rec = st2[e];
        float wt = __int_as_float(rec.y);
        ushort4 v = ((const ushort4*)(srcb + (size_t)rec.x * HID))[q];
        acc.x += wt * bf2f(v.x);
        acc.y += wt * bf2f(v.y);
        acc.z += wt * bf2f(v.z);
        acc.w += wt * bf2f(v.w);
    }
#pragma unroll
    for (int off = 4; off < 64; off <<= 1) {
        acc.x += __shfl_xor(acc.x, off, 64);
        acc.y += __shfl_xor(acc.y, off, 64);
        acc.z += __shfl_xor(acc.z, off, 64);
        acc.w += __shfl_xor(acc.w, off, 64);
    }
    if (i == 0) {
        float d = dinv[n];
        ushort4 sv = ((const ushort4*)(srcb + (size_t)n * HID))[q];
        float4 bq = ((const float4*)bias)[q];
        float r0 = d * fmaxf(d * (acc.x + bf2f(sv.x)) + bq.x, 0.f);
        float r1 = d * fmaxf(d * (acc.y + bf2f(sv.y)) + bq.y, 0.f);
        float r2 = d * fmaxf(d * (acc.z + bf2f(sv.z)) + bq.z, 0.f);
        float r3 = d * fmaxf(d * (acc.w + bf2f(sv.w)) + bq.w, 0.f);
        ((ushort4*)(dstb + (size_t)n * HID))[q] =
            make_ushort4(f2bf(r0), f2bf(r1), f2bf(r2), f2bf(r3));
    }
}

// ---------------------------------------------------------------------------
// K7: layer-2 aggregate fused with W2 matvec + bias + log_softmax.
// ---------------------------------------------------------------------------
__global__ __launch_bounds__(256) void k_agg2(const int* __restrict__ offs,
                                              const int2* __restrict__ st2,
                                              const float* __restrict__ dinv,
                                              const unsigned short* __restrict__ srcb,
                                              const float* __restrict__ W2,
                                              const float* __restrict__ b2,
                                              float* __restrict__ out, int N) {
    __shared__ float Ws[HID * C_OUT];
    __shared__ float bs[C_OUT];
    int t = threadIdx.x;
    for (int iw = t; iw < HID * C_OUT; iw += 256) Ws[iw] = W2[iw];
    if (t < C_OUT) bs[t] = b2[t];
    __syncthreads();

    int lane = t & 63, w = t >> 6;
    int n = blockIdx.x * 4 + w;
    if (n >= N) return;
    int q = lane & 3, i = lane >> 2;
    int beg = offs[n], end = offs[n + 1];
    float4 acc = make_float4(0.f, 0.f, 0.f, 0.f);
    for (int e = beg + i; e < end; e += 16) {
        int2 rec = st2[e];
        float wt = __int_as_float(rec.y);
        ushort4 v = ((const ushort4*)(srcb + (size_t)rec.x * HID))[q];
        acc.x += wt * bf2f(v.x);
        acc.y += wt * bf2f(v.y);
        acc.z += wt * bf2f(v.z);
        acc.w += wt * bf2f(v.w);
    }
#pragma unroll
    for (int off = 4; off < 64; off <<= 1) {
        acc.x += __shfl_xor(acc.x, off, 64);
        acc.y += __shfl_xor(acc.y, off, 64);
        acc.z += __shfl_xor(acc.z, off, 64);
        acc.w += __shfl_xor(acc.w, off, 64);
    }
    // every lane now holds the full sum for its quad q
    float d = dinv[n];
    ushort4 sv = ((const ushort4*)(srcb + (size_t)n * HID))[q];
    float gq[4];
    gq[0] = d * (acc.x + bf2f(sv.x));
    gq[1] = d * (acc.y + bf2f(sv.y));
    gq[2] = d * (acc.z + bf2f(sv.z));
    gq[3] = d * (acc.w + bf2f(sv.w));
    // assemble all 16 dims in every lane (quads live in lanes base..base+3)
    float g16[16];
    int base = lane & ~3;
#pragma unroll
    for (int qq = 0; qq < 4; ++qq) {
#pragma unroll
        for (int k = 0; k < 4; ++k)
            g16[qq * 4 + k] = __shfl(gq[k], base + qq, 64);
    }
    float logit = -INFINITY;
    if (lane < C_OUT) {
        float a = bs[lane];
#pragma unroll
        for (int j = 0; j < HID; ++j) a += g16[j] * Ws[j * C_OUT + lane];
        logit = a;
    }
    float m = logit;
#pragma unroll
    for (int off = 32; off > 0; off >>= 1) m = fmaxf(m, __shfl_xor(m, off, 64));
    float ex = (lane < C_OUT) ? __expf(logit - m) : 0.0f;
    float s = ex;
#pragma unroll
    for (int off = 32; off > 0; off >>= 1) s += __shfl_xor(s, off, 64);
    if (lane < C_OUT) out[(size_t)n * C_OUT + lane] = logit - m - __logf(s);
}

// ---------------------------------------------------------------------------
extern "C" void kernel_launch(void* const* d_in, const int* in_sizes, int n_in,
                              void* d_out, int out_size, void* d_ws, size_t ws_size,
                              hipStream_t stream) {
    const float* x   = (const float*)d_in[0];
    const int*   ei  = (const int*)d_in[1];
    const float* ew  = (const float*)d_in[2];
    const float* W1  = (const float*)d_in[3];
    const float* b1  = (const float*)d_in[4];
    const float* W2  = (const float*)d_in[5];
    const float* b2  = (const float*)d_in[6];
    float* out = (float*)d_out;

    const int N = in_sizes[0] / F_IN;          // 100000
    const int E = in_sizes[2];                 // 3200000
    const int* row = ei;
    const int* col = ei + E;
    const int NB = (N + BNODES - 1) >> BSH;    // 782

    // workspace carve (4-byte words)
    int* wsi = (int*)d_ws;
    size_t o = 0;
    int* gcnt  = wsi + o; o += MAXNB;
    int* bo    = wsi + o; o += MAXNB + 1;
    int* bcur  = wsi + o; o += MAXNB;
    int* offs  = wsi + o; o += (size_t)N + 8;
    float* dinv = (float*)(wsi + o); o += N;
    unsigned short* h1b = (unsigned short*)(wsi + o); o += (size_t)N * HID / 2;
    unsigned short* a1b = (unsigned short*)(wsi + o); o += (size_t)N * HID / 2;
    int2* st   = (int2*)(wsi + o); o += (size_t)E * 2;
    int2* st2  = (int2*)(wsi + o); o += (size_t)E * 2;

    int gC = (E + EPB - 1) / EPB;              // 391
    int gW = (N + 3) / 4;                      // 25000

    k_zero<<<1, 1024, 0, stream>>>(gcnt, NB);
    k_count<<<gC, CTH, 0, stream>>>(col, gcnt, E, NB);
    k_scan<<<1, 1024, 0, stream>>>(gcnt, bo, bcur, offs, NB, N, E);
    k_part<<<gC, CTH, 0, stream>>>(row, col, ew, bcur, st, E, NB);
    k_sort<<<NB, 256, 0, stream>>>(bo, st, st2, offs, dinv, N);
    k_gemm1<<<(N + 255) / 256, 256, 0, stream>>>(x, W1, dinv, h1b, N);
    k_agg1<<<gW, 256, 0, stream>>>(offs, st2, dinv, h1b, b1, a1b, N);
    k_agg2<<<gW, 256, 0, stream>>>(offs, st2, dinv, a1b, W2, b2, out, N);
}